// Round 7
// baseline (1338.532 us; speedup 1.0000x reference)
//
#include <hip/hip_runtime.h>
#include <hip/hip_bf16.h>
#include <stdint.h>
#include <stddef.h>

// ---------------------------------------------------------------------------
// Connectivity3D: PointNet (6->64->128->256, BN folded, max-pool) ->
// object_embedding -> 2x GCN -> edge MLP -> tanh -> [512,16,16].
//
// Algebraic collapse: dense intra-object edges => deg=16 for every node =>
// GCN output = (per-object mean of xw) + b, identical for all 16 parts =>
// ONE edge score per object; only fsum[obj] = sum_parts feat is needed.
//
// R7 = R6's 2-barrier phase structure with the spill fixed (R6: 1.27 GB
// scratch traffic, af1[4]+long-lived prefetch pushed past the 128-reg
// waves_per_eu(4,4) budget):
//  - L1 stays CHANNEL-partitioned (af1 = 1 frag = 4 regs, as R5); its
//    B-fragment (16 points x 6ch+bias) is built directly from global by
//    q==0 lanes -> x LDS buffer eliminated.
//  - Single h1 buffer: phase A = L2 (last reader of h1); phase B = L3 +
//    L1(cg+1) writes h1. Barrier after A makes this safe. 2 barriers/iter.
//  - Prefetch interleaved 2 tiles at a time (12 f32 live, not 24).
//  - LDS 52 KB (h1 18 KB + h2 34 KB) -> 2 blocks/CU.
// ---------------------------------------------------------------------------

typedef short bf16x8 __attribute__((ext_vector_type(8)));
typedef short bf16x4 __attribute__((ext_vector_type(4)));
typedef float f32x4  __attribute__((ext_vector_type(4)));

// workspace byte offsets (all 16B aligned)
#define WT1_OFF   0u        // bf16 [64][32]  (W1*g1)^T, col6 = bias, cols7-31 = 0
#define WT2_OFF   4096u     // bf16 [128][64] (W2*g2)^T
#define WT3_OFF   20480u    // bf16 [256][128](W3*g3)^T
#define B1F_OFF   86016u    // f32 [64] (unused by pointnet; kept for layout)
#define B2F_OFF   86272u    // f32 [128]
#define B3F_OFF   86784u    // f32 [256]
#define FSUM_OFF  87808u    // f32 [512][256]
#define WC1S_OFF  612096u   // f32 [256][256] Wc1[0:256]+Wc1[256:512]

__device__ __forceinline__ unsigned short f2bf(float f) {
  union { float f; unsigned u; } v; v.f = f;
  unsigned r = v.u + 0x7fffu + ((v.u >> 16) & 1u);   // round-to-nearest-even
  return (unsigned short)(r >> 16);
}

__device__ __forceinline__ bf16x4 pack_relu4(f32x4 d) {
  __hip_bfloat162 lo = __float22bfloat162_rn(make_float2(fmaxf(d.x, 0.f), fmaxf(d.y, 0.f)));
  __hip_bfloat162 hi = __float22bfloat162_rn(make_float2(fmaxf(d.z, 0.f), fmaxf(d.w, 0.f)));
  union { bf16x4 v; __hip_bfloat162 h[2]; } u;
  u.h[0] = lo; u.h[1] = hi;
  return u.v;
}

// ---------------------------------------------------------------------------
__global__ void prep_kernel(
    const float* __restrict__ W1, const float* __restrict__ b1,
    const float* __restrict__ g1, const float* __restrict__ bt1,
    const float* __restrict__ W2, const float* __restrict__ b2,
    const float* __restrict__ g2, const float* __restrict__ bt2,
    const float* __restrict__ W3, const float* __restrict__ b3,
    const float* __restrict__ g3, const float* __restrict__ bt3,
    const float* __restrict__ Wc1, unsigned char* __restrict__ ws)
{
  unsigned short* wt1 = (unsigned short*)(ws + WT1_OFF);
  unsigned short* wt2 = (unsigned short*)(ws + WT2_OFF);
  unsigned short* wt3 = (unsigned short*)(ws + WT3_OFF);
  float* b1f  = (float*)(ws + B1F_OFF);
  float* b2f  = (float*)(ws + B2F_OFF);
  float* b3f  = (float*)(ws + B3F_OFF);
  float* wc1s = (float*)(ws + WC1S_OFF);

  int i = blockIdx.x * 256 + threadIdx.x;
  if (i < 2048) { int o = i >> 5, c = i & 31;                 // wt1[o][c]
    float v = (c < 6) ? W1[c*64 + o] * g1[o]
            : (c == 6 ? (b1[o]*g1[o] + bt1[o]) : 0.f);        // bias-in-col6
    wt1[i] = f2bf(v); return; }
  i -= 2048;
  if (i < 8192) { int o = i >> 6, c = i & 63;                 // wt2[o][c]
    wt2[i] = f2bf(W2[c*128 + o] * g2[o]); return; }
  i -= 8192;
  if (i < 32768) { int o = i >> 7, c = i & 127;               // wt3[o][c]
    wt3[i] = f2bf(W3[c*256 + o] * g3[o]); return; }
  i -= 32768;
  if (i < 64)  { b1f[i] = b1[i]*g1[i] + bt1[i]; return; }
  i -= 64;
  if (i < 128) { b2f[i] = b2[i]*g2[i] + bt2[i]; return; }
  i -= 128;
  if (i < 256) { b3f[i] = b3[i]*g3[i] + bt3[i]; return; }
  i -= 256;
  if (i < 65536) { wc1s[i] = Wc1[i] + Wc1[i + 65536]; }
}

// ---------------------------------------------------------------------------
// One block per object: 512 blocks x 512 thr (8 waves), 8192 pts, chunk=128,
// 64 iterations, 2 barriers/iter.
//   phase A: L2 (h1 -> h2), ch-partitioned (wave w: ch-tile w).
//   phase B: L3 (h2 -> macc), ch-partitioned (wave w: out-tiles 2w,2w+1)
//            + L1(cg+1), ch-partitioned (wave w: ch-tile w&3, pt-half w>>2,
//              B built from global by q==0 lanes), writes h1 (safe: h1's
//              last reads were in phase A, barrier between).
// LDS shorts: h1 @0 [128][72], h2 @9216 [128][136]  -> 53248 B total
#define LDSH1 0
#define LDSH2 9216

__global__ __launch_bounds__(512)
__attribute__((amdgpu_waves_per_eu(4, 4)))
void pointnet_kernel(
    const float* __restrict__ pcls, const unsigned char* __restrict__ ws,
    float* __restrict__ fsum)
{
  __shared__ __align__(16) unsigned short lds[26624];   // 53248 B -> 2 blocks/CU

  const unsigned short* wt1 = (const unsigned short*)(ws + WT1_OFF);
  const unsigned short* wt2 = (const unsigned short*)(ws + WT2_OFF);
  const unsigned short* wt3 = (const unsigned short*)(ws + WT3_OFF);
  const float* b2f = (const float*)(ws + B2F_OFF);
  const float* b3f = (const float*)(ws + B3F_OFF);

  const int tid  = threadIdx.x;
  const int w    = tid >> 6;        // wave 0..7
  const int lane = tid & 63;
  const int l15  = lane & 15;
  const int q    = lane >> 4;       // quad 0..3
  const int obj  = blockIdx.x;

  const int c1t = w & 3;            // L1 ch-tile
  const int ph  = w >> 2;           // L1 pt-half (pt-tiles ph*4 .. ph*4+3)

  // Weight A-fragments, register-resident. A[m=l15][k=q*8+j].
  bf16x8 af1 = *(const bf16x8*)(wt1 + (c1t*16 + l15)*32 + q*8);
  bf16x8 af2[2], af3[2][4];
#pragma unroll
  for (int kf = 0; kf < 2; ++kf)
    af2[kf] = *(const bf16x8*)(wt2 + (w*16 + l15)*64 + kf*32 + q*8);
#pragma unroll
  for (int nt = 0; nt < 2; ++nt)
#pragma unroll
    for (int kf = 0; kf < 4; ++kf)
      af3[nt][kf] = *(const bf16x8*)(wt3 + ((2*w + nt)*16 + l15)*128 + kf*32 + q*8);

  const f32x4 bias2 = *(const f32x4*)(b2f + w*16 + q*4);

  const float* pbase = pcls + (size_t)obj * 49152;   // 8192 pts * 6
  // q==0 lanes load point (cg*128 + (ph*4+i)*16 + l15); 6 floats each
  const float* pmine = pbase + ((ph*4)*16 + l15)*6;
  const bool  ld = (q == 0);

  // ---- L1 for chunk 0 (prologue): 4 pt-tiles, B from global
#pragma unroll
  for (int i = 0; i < 4; ++i) {
    float2 f01, f23, f45;
    if (ld) {
      const float* pp = pmine + i*96;          // 16 pts * 6 floats per tile
      f01 = *(const float2*)(pp);
      f23 = *(const float2*)(pp + 2);
      f45 = *(const float2*)(pp + 4);
    }
    bf16x8 bx = (bf16x8){0,0,0,0,0,0,0,0};
    if (ld) {
      union { bf16x8 v; __hip_bfloat162 h[4]; } u;
      u.h[0] = __float22bfloat162_rn(f01);
      u.h[1] = __float22bfloat162_rn(f23);
      u.h[2] = __float22bfloat162_rn(f45);
      u.h[3] = __float22bfloat162_rn(make_float2(1.f, 0.f));  // bias ch, pad
      bx = u.v;
    }
    f32x4 d = {0.f, 0.f, 0.f, 0.f};
    d = __builtin_amdgcn_mfma_f32_16x16x32_bf16(af1, bx, d, 0, 0, 0);
    *(bf16x4*)(&lds[LDSH1 + ((ph*4 + i)*16 + l15)*72 + c1t*16 + q*4]) = pack_relu4(d);
  }
  __syncthreads();

  f32x4 macc[2];
  float sacc[2][4];
#pragma unroll
  for (int nt = 0; nt < 2; ++nt) {
    macc[nt] = (f32x4){-3e38f, -3e38f, -3e38f, -3e38f};
#pragma unroll
    for (int r = 0; r < 4; ++r) sacc[nt][r] = 0.f;
  }

  for (int cg = 0; cg < 64; ++cg) {
    // ---- phase A: layer 2 (64->128, relu). Wave: ch-tile w, all 8 pt-tiles
#pragma unroll
    for (int pt = 0; pt < 8; ++pt) {
      bf16x8 b0  = *(const bf16x8*)(&lds[LDSH1 + (pt*16 + l15)*72 + q*8]);
      bf16x8 b1v = *(const bf16x8*)(&lds[LDSH1 + (pt*16 + l15)*72 + 32 + q*8]);
      f32x4 d = bias2;
      d = __builtin_amdgcn_mfma_f32_16x16x32_bf16(af2[0], b0,  d, 0, 0, 0);
      d = __builtin_amdgcn_mfma_f32_16x16x32_bf16(af2[1], b1v, d, 0, 0, 0);
      *(bf16x4*)(&lds[LDSH2 + (pt*16 + l15)*136 + w*16 + q*4]) = pack_relu4(d);
    }
    __syncthreads();                 // h1 reads + h2 writes complete

    const int havenext = (cg < 63);
    const float* pnext = pmine + (cg + 1)*768;

    // ---- phase B, half 1: prefetch L1 tiles 0,1; L3 pts 0..3
    float2 fa01, fa23, fa45, fb01, fb23, fb45;
    if (havenext && ld) {
      fa01 = *(const float2*)(pnext);
      fa23 = *(const float2*)(pnext + 2);
      fa45 = *(const float2*)(pnext + 4);
      fb01 = *(const float2*)(pnext + 96);
      fb23 = *(const float2*)(pnext + 98);
      fb45 = *(const float2*)(pnext + 100);
    }
#pragma unroll
    for (int pt = 0; pt < 4; ++pt) {
      bf16x8 b[4];
#pragma unroll
      for (int kf = 0; kf < 4; ++kf)
        b[kf] = *(const bf16x8*)(&lds[LDSH2 + (pt*16 + l15)*136 + kf*32 + q*8]);
#pragma unroll
      for (int nt = 0; nt < 2; ++nt) {
        f32x4 d = {0.f, 0.f, 0.f, 0.f};
#pragma unroll
        for (int kf = 0; kf < 4; ++kf)
          d = __builtin_amdgcn_mfma_f32_16x16x32_bf16(af3[nt][kf], b[kf], d, 0, 0, 0);
#pragma unroll
        for (int r = 0; r < 4; ++r)
          macc[nt][r] = fmaxf(macc[nt][r], d[r]);
      }
    }
    if (havenext) {
      bf16x8 bx0 = (bf16x8){0,0,0,0,0,0,0,0}, bx1 = bx0;
      if (ld) {
        union { bf16x8 v; __hip_bfloat162 h[4]; } u;
        u.h[0] = __float22bfloat162_rn(fa01);
        u.h[1] = __float22bfloat162_rn(fa23);
        u.h[2] = __float22bfloat162_rn(fa45);
        u.h[3] = __float22bfloat162_rn(make_float2(1.f, 0.f));
        bx0 = u.v;
        u.h[0] = __float22bfloat162_rn(fb01);
        u.h[1] = __float22bfloat162_rn(fb23);
        u.h[2] = __float22bfloat162_rn(fb45);
        u.h[3] = __float22bfloat162_rn(make_float2(1.f, 0.f));
        bx1 = u.v;
      }
      f32x4 d0 = {0.f, 0.f, 0.f, 0.f}, d1 = d0;
      d0 = __builtin_amdgcn_mfma_f32_16x16x32_bf16(af1, bx0, d0, 0, 0, 0);
      d1 = __builtin_amdgcn_mfma_f32_16x16x32_bf16(af1, bx1, d1, 0, 0, 0);
      *(bf16x4*)(&lds[LDSH1 + ((ph*4 + 0)*16 + l15)*72 + c1t*16 + q*4]) = pack_relu4(d0);
      *(bf16x4*)(&lds[LDSH1 + ((ph*4 + 1)*16 + l15)*72 + c1t*16 + q*4]) = pack_relu4(d1);
    }

    // ---- phase B, half 2: prefetch L1 tiles 2,3; L3 pts 4..7
    if (havenext && ld) {
      fa01 = *(const float2*)(pnext + 192);
      fa23 = *(const float2*)(pnext + 194);
      fa45 = *(const float2*)(pnext + 196);
      fb01 = *(const float2*)(pnext + 288);
      fb23 = *(const float2*)(pnext + 290);
      fb45 = *(const float2*)(pnext + 292);
    }
#pragma unroll
    for (int pt = 4; pt < 8; ++pt) {
      bf16x8 b[4];
#pragma unroll
      for (int kf = 0; kf < 4; ++kf)
        b[kf] = *(const bf16x8*)(&lds[LDSH2 + (pt*16 + l15)*136 + kf*32 + q*8]);
#pragma unroll
      for (int nt = 0; nt < 2; ++nt) {
        f32x4 d = {0.f, 0.f, 0.f, 0.f};
#pragma unroll
        for (int kf = 0; kf < 4; ++kf)
          d = __builtin_amdgcn_mfma_f32_16x16x32_bf16(af3[nt][kf], b[kf], d, 0, 0, 0);
#pragma unroll
        for (int r = 0; r < 4; ++r)
          macc[nt][r] = fmaxf(macc[nt][r], d[r]);
      }
    }
    if (havenext) {
      bf16x8 bx0 = (bf16x8){0,0,0,0,0,0,0,0}, bx1 = bx0;
      if (ld) {
        union { bf16x8 v; __hip_bfloat162 h[4]; } u;
        u.h[0] = __float22bfloat162_rn(fa01);
        u.h[1] = __float22bfloat162_rn(fa23);
        u.h[2] = __float22bfloat162_rn(fa45);
        u.h[3] = __float22bfloat162_rn(make_float2(1.f, 0.f));
        bx0 = u.v;
        u.h[0] = __float22bfloat162_rn(fb01);
        u.h[1] = __float22bfloat162_rn(fb23);
        u.h[2] = __float22bfloat162_rn(fb45);
        u.h[3] = __float22bfloat162_rn(make_float2(1.f, 0.f));
        bx1 = u.v;
      }
      f32x4 d0 = {0.f, 0.f, 0.f, 0.f}, d1 = d0;
      d0 = __builtin_amdgcn_mfma_f32_16x16x32_bf16(af1, bx0, d0, 0, 0, 0);
      d1 = __builtin_amdgcn_mfma_f32_16x16x32_bf16(af1, bx1, d1, 0, 0, 0);
      *(bf16x4*)(&lds[LDSH1 + ((ph*4 + 2)*16 + l15)*72 + c1t*16 + q*4]) = pack_relu4(d0);
      *(bf16x4*)(&lds[LDSH1 + ((ph*4 + 3)*16 + l15)*72 + c1t*16 + q*4]) = pack_relu4(d1);
    }

    // part boundary (512 pts = 4 chunks): reduce max over the 16 pt-lanes
    if ((cg & 3) == 3) {
#pragma unroll
      for (int nt = 0; nt < 2; ++nt) {
#pragma unroll
        for (int r = 0; r < 4; ++r) {
          float v = macc[nt][r];
          v = fmaxf(v, __shfl_xor(v, 1));
          v = fmaxf(v, __shfl_xor(v, 2));
          v = fmaxf(v, __shfl_xor(v, 4));
          v = fmaxf(v, __shfl_xor(v, 8));
          sacc[nt][r] += v;
        }
        macc[nt] = (f32x4){-3e38f, -3e38f, -3e38f, -3e38f};
      }
    }
    __syncthreads();                 // h2 reads + h1(cg+1) writes complete
  }

  // fsum[ch] = sum_parts max + 16*b3 (bias3 folded post-max; 16 parts/object)
#pragma unroll
  for (int r = 0; r < 4; ++r) {
    if (l15 == r) {
#pragma unroll
      for (int nt = 0; nt < 2; ++nt) {
        const int ch = (2*w + nt)*16 + q*4 + r;
        fsum[obj*256 + ch] = sacc[nt][r] + 16.f * b3f[ch];
      }
    }
  }
}

// ---------------------------------------------------------------------------
// 4 objects per block (128 blocks): weights read once per 4 objects.
// Ping-pong: bufA=fsum -> (We) bufB=esum -> (Wg1) bufA=x1 -> (Wg2) bufB=x2
// -> (Wc1s) bufA=h -> (Wc2) regs h2 -> dot Wc3 -> tanh -> fill 16x16.
__global__ __launch_bounds__(256) void objmlp_kernel(
    const float* __restrict__ We,  const float* __restrict__ be,
    const float* __restrict__ Wg1, const float* __restrict__ bg1,
    const float* __restrict__ Wg2, const float* __restrict__ bg2,
    const float* __restrict__ bc1,
    const float* __restrict__ Wc2, const float* __restrict__ bc2,
    const float* __restrict__ Wc3, const float* __restrict__ bc3,
    const unsigned char* __restrict__ ws, float* __restrict__ out)
{
  const float* fsum = (const float*)(ws + FSUM_OFF);
  const float* Wc1s = (const float*)(ws + WC1S_OFF);
  __shared__ float bufA[4][256], bufB[4][256], red[4][4];
  __shared__ float cval[4];
  const int t = threadIdx.x, ob = blockIdx.x * 4;

#pragma unroll
  for (int o = 0; o < 4; ++o) bufA[o][t] = fsum[(ob + o)*256 + t];
  __syncthreads();

  float acc[4];
  // phase 1: We: bufA(fsum) -> bufB(esum)
#pragma unroll
  for (int o = 0; o < 4; ++o) acc[o] = 0.f;
#pragma unroll 8
  for (int c = 0; c < 256; ++c) {
    float wv = We[c*256 + t];
#pragma unroll
    for (int o = 0; o < 4; ++o) acc[o] += bufA[o][c] * wv;
  }
#pragma unroll
  for (int o = 0; o < 4; ++o) bufB[o][t] = acc[o] + 16.f * be[t];
  __syncthreads();

  // phase 2: Wg1: bufB(esum) -> bufA(x1 = relu(gcn1))
#pragma unroll
  for (int o = 0; o < 4; ++o) acc[o] = 0.f;
#pragma unroll 8
  for (int c = 0; c < 256; ++c) {
    float wv = Wg1[c*256 + t];
#pragma unroll
    for (int o = 0; o < 4; ++o) acc[o] += bufB[o][c] * wv;
  }
#pragma unroll
  for (int o = 0; o < 4; ++o) bufA[o][t] = fmaxf(acc[o] * 0.0625f + bg1[t], 0.f);
  __syncthreads();

  // phase 3: Wg2: bufA(x1) -> bufB(x2)
#pragma unroll
  for (int o = 0; o < 4; ++o) acc[o] = 0.f;
#pragma unroll 8
  for (int c = 0; c < 256; ++c) {
    float wv = Wg2[c*256 + t];
#pragma unroll
    for (int o = 0; o < 4; ++o) acc[o] += bufA[o][c] * wv;
  }
#pragma unroll
  for (int o = 0; o < 4; ++o) bufB[o][t] = acc[o] + bg2[t];
  __syncthreads();

  // phase 4: Wc1s: bufB(x2) -> bufA(h)
#pragma unroll
  for (int o = 0; o < 4; ++o) acc[o] = 0.f;
#pragma unroll 8
  for (int c = 0; c < 256; ++c) {
    float wv = Wc1s[c*256 + t];
#pragma unroll
    for (int o = 0; o < 4; ++o) acc[o] += bufB[o][c] * wv;
  }
#pragma unroll
  for (int o = 0; o < 4; ++o) bufA[o][t] = fmaxf(acc[o] + bc1[t], 0.f);
  __syncthreads();

  // phase 5: Wc2: bufA(h) -> h2 (regs)
#pragma unroll
  for (int o = 0; o < 4; ++o) acc[o] = 0.f;
#pragma unroll 8
  for (int c = 0; c < 256; ++c) {
    float wv = Wc2[c*256 + t];
#pragma unroll
    for (int o = 0; o < 4; ++o) acc[o] += bufA[o][c] * wv;
  }

  // dot with Wc3, wave reduce, tanh
  float w3 = Wc3[t];
#pragma unroll
  for (int o = 0; o < 4; ++o) {
    float part = fmaxf(acc[o] + bc2[t], 0.f) * w3;
#pragma unroll
    for (int off = 1; off < 64; off <<= 1) part += __shfl_xor(part, off);
    if ((t & 63) == 0) red[o][t >> 6] = part;
  }
  __syncthreads();
  if (t < 4) cval[t] = tanhf(red[t][0] + red[t][1] + red[t][2] + red[t][3] + bc3[0]);
  __syncthreads();

  const bool diag = (t >> 4) == (t & 15);
#pragma unroll
  for (int o = 0; o < 4; ++o)
    out[(ob + o)*256 + t] = diag ? 0.f : cval[o];
}

// ---------------------------------------------------------------------------
extern "C" void kernel_launch(void* const* d_in, const int* in_sizes, int n_in,
                              void* d_out, int out_size, void* d_ws, size_t ws_size,
                              hipStream_t stream) {
  const float* pcls = (const float*)d_in[0];
  const float* W1 = (const float*)d_in[1];  const float* b1 = (const float*)d_in[2];
  const float* g1 = (const float*)d_in[3];  const float* bt1 = (const float*)d_in[4];
  const float* W2 = (const float*)d_in[5];  const float* b2 = (const float*)d_in[6];
  const float* g2 = (const float*)d_in[7];  const float* bt2 = (const float*)d_in[8];
  const float* W3 = (const float*)d_in[9];  const float* b3 = (const float*)d_in[10];
  const float* g3 = (const float*)d_in[11]; const float* bt3 = (const float*)d_in[12];
  const float* We = (const float*)d_in[13]; const float* be = (const float*)d_in[14];
  const float* Wg1 = (const float*)d_in[15]; const float* bg1 = (const float*)d_in[16];
  const float* Wg2 = (const float*)d_in[17]; const float* bg2 = (const float*)d_in[18];
  const float* Wc1 = (const float*)d_in[19]; const float* bc1 = (const float*)d_in[20];
  const float* Wc2 = (const float*)d_in[21]; const float* bc2 = (const float*)d_in[22];
  const float* Wc3 = (const float*)d_in[23]; const float* bc3 = (const float*)d_in[24];
  unsigned char* ws = (unsigned char*)d_ws;
  float* out = (float*)d_out;

  prep_kernel<<<426, 256, 0, stream>>>(W1, b1, g1, bt1, W2, b2, g2, bt2,
                                       W3, b3, g3, bt3, Wc1, ws);
  pointnet_kernel<<<512, 512, 0, stream>>>(pcls, ws, (float*)(ws + FSUM_OFF));
  objmlp_kernel<<<128, 256, 0, stream>>>(We, be, Wg1, bg1, Wg2, bg2, bc1,
                                         Wc2, bc2, Wc3, bc3, ws, out);
}

// Round 8
// 500.694 us; speedup vs baseline: 2.6734x; 2.6734x over previous
//
#include <hip/hip_runtime.h>
#include <hip/hip_bf16.h>
#include <stdint.h>
#include <stddef.h>

// ---------------------------------------------------------------------------
// Connectivity3D: PointNet (6->64->128->256, BN folded, max-pool) ->
// object_embedding -> 2x GCN -> edge MLP -> tanh -> [512,16,16].
//
// Algebraic collapse: dense intra-object edges => deg=16 for every node =>
// GCN output = (per-object mean of xw) + b, identical for all 16 parts =>
// ONE edge score per object; only fsum[obj] = sum_parts feat is needed.
//
// R8 = pointnet main loop reverted to EXACT R5 (353 us, spill-free; R6/R7
// proved the structure is at the waves_per_eu(4,4) 128-reg ceiling — any
// added live state spills catastrophically). New: the per-object MLP is
// merged into the pointnet block as an epilogue (each block owns all 256
// fsum channels of its object -> no grid sync needed). 3 kernels -> 2;
// fsum and wc1s never touch HBM; prep shrinks to weight conversion only.
// ---------------------------------------------------------------------------

typedef short bf16x8 __attribute__((ext_vector_type(8)));
typedef short bf16x4 __attribute__((ext_vector_type(4)));
typedef float f32x4  __attribute__((ext_vector_type(4)));

// workspace byte offsets (all 16B aligned)
#define WT1_OFF   0u        // bf16 [64][32]  (W1*g1)^T, col6 = bias, cols7-31 = 0
#define WT2_OFF   4096u     // bf16 [128][64] (W2*g2)^T
#define WT3_OFF   20480u    // bf16 [256][128](W3*g3)^T
#define B1F_OFF   86016u    // f32 [64] (unused; layout keep)
#define B2F_OFF   86272u    // f32 [128]
#define B3F_OFF   86784u    // f32 [256]

__device__ __forceinline__ unsigned short f2bf(float f) {
  union { float f; unsigned u; } v; v.f = f;
  unsigned r = v.u + 0x7fffu + ((v.u >> 16) & 1u);   // round-to-nearest-even
  return (unsigned short)(r >> 16);
}

__device__ __forceinline__ bf16x4 pack_relu4(f32x4 d) {
  __hip_bfloat162 lo = __float22bfloat162_rn(make_float2(fmaxf(d.x, 0.f), fmaxf(d.y, 0.f)));
  __hip_bfloat162 hi = __float22bfloat162_rn(make_float2(fmaxf(d.z, 0.f), fmaxf(d.w, 0.f)));
  union { bf16x4 v; __hip_bfloat162 h[2]; } u;
  u.h[0] = lo; u.h[1] = hi;
  return u.v;
}

// ---------------------------------------------------------------------------
__global__ void prep_kernel(
    const float* __restrict__ W1, const float* __restrict__ b1,
    const float* __restrict__ g1, const float* __restrict__ bt1,
    const float* __restrict__ W2, const float* __restrict__ b2,
    const float* __restrict__ g2, const float* __restrict__ bt2,
    const float* __restrict__ W3, const float* __restrict__ b3,
    const float* __restrict__ g3, const float* __restrict__ bt3,
    unsigned char* __restrict__ ws)
{
  unsigned short* wt1 = (unsigned short*)(ws + WT1_OFF);
  unsigned short* wt2 = (unsigned short*)(ws + WT2_OFF);
  unsigned short* wt3 = (unsigned short*)(ws + WT3_OFF);
  float* b1f  = (float*)(ws + B1F_OFF);
  float* b2f  = (float*)(ws + B2F_OFF);
  float* b3f  = (float*)(ws + B3F_OFF);

  int i = blockIdx.x * 256 + threadIdx.x;
  if (i < 2048) { int o = i >> 5, c = i & 31;                 // wt1[o][c]
    float v = (c < 6) ? W1[c*64 + o] * g1[o]
            : (c == 6 ? (b1[o]*g1[o] + bt1[o]) : 0.f);        // bias-in-col6
    wt1[i] = f2bf(v); return; }
  i -= 2048;
  if (i < 8192) { int o = i >> 6, c = i & 63;                 // wt2[o][c]
    wt2[i] = f2bf(W2[c*128 + o] * g2[o]); return; }
  i -= 8192;
  if (i < 32768) { int o = i >> 7, c = i & 127;               // wt3[o][c]
    wt3[i] = f2bf(W3[c*256 + o] * g3[o]); return; }
  i -= 32768;
  if (i < 64)  { b1f[i] = b1[i]*g1[i] + bt1[i]; return; }
  i -= 64;
  if (i < 128) { b2f[i] = b2[i]*g2[i] + bt2[i]; return; }
  i -= 128;
  if (i < 256) { b3f[i] = b3[i]*g3[i] + bt3[i]; }
}

// ---------------------------------------------------------------------------
// One block per object: 512 blocks x 512 thr (8 waves), 8192 pts, chunk=128,
// 64 iterations, 3 barriers/iter (EXACT R5 structure). Then in-block MLP
// epilogue (per-object GCN+connectivity head) and direct out write.
// LDS [pt][ch] bf16: x[128][40] @0, h1[128][72] @5120, h2[128][136] @14336
#define LDSX  0
#define LDSH1 5120
#define LDSH2 14336

__global__ __launch_bounds__(512)
__attribute__((amdgpu_waves_per_eu(4, 4)))
void pointnet_fused_kernel(
    const float* __restrict__ pcls, const unsigned char* __restrict__ ws,
    const float* __restrict__ We,  const float* __restrict__ be,
    const float* __restrict__ Wg1, const float* __restrict__ bg1,
    const float* __restrict__ Wg2, const float* __restrict__ bg2,
    const float* __restrict__ Wc1, const float* __restrict__ bc1,
    const float* __restrict__ Wc2, const float* __restrict__ bc2,
    const float* __restrict__ Wc3, const float* __restrict__ bc3,
    float* __restrict__ out)
{
  __shared__ __align__(16) unsigned short lds[31744];   // 62 KB -> 2 blocks/CU

  const unsigned short* wt1 = (const unsigned short*)(ws + WT1_OFF);
  const unsigned short* wt2 = (const unsigned short*)(ws + WT2_OFF);
  const unsigned short* wt3 = (const unsigned short*)(ws + WT3_OFF);
  const float* b2f = (const float*)(ws + B2F_OFF);
  const float* b3f = (const float*)(ws + B3F_OFF);

  const int tid  = threadIdx.x;
  const int w    = tid >> 6;        // wave 0..7
  const int lane = tid & 63;
  const int l15  = lane & 15;
  const int q    = lane >> 4;       // quad 0..3
  const int obj  = blockIdx.x;

  const int c1t = w & 3;            // L1 ch-tile
  const int ph  = w >> 2;           // L1 pt-half

  // Weight A-fragments, register-resident. A[m=l15][k=q*8+j].
  bf16x8 af1 = *(const bf16x8*)(wt1 + (c1t*16 + l15)*32 + q*8);
  bf16x8 af2[2], af3[2][4];
#pragma unroll
  for (int kf = 0; kf < 2; ++kf)
    af2[kf] = *(const bf16x8*)(wt2 + (w*16 + l15)*64 + kf*32 + q*8);
#pragma unroll
  for (int nt = 0; nt < 2; ++nt)
#pragma unroll
    for (int kf = 0; kf < 4; ++kf)
      af3[nt][kf] = *(const bf16x8*)(wt3 + ((2*w + nt)*16 + l15)*128 + kf*32 + q*8);

  const f32x4 bias2 = *(const f32x4*)(b2f + w*16 + q*4);

  // point staging: 768 floats/chunk; thread covers i=tid, (tid<256) i=512+tid
  const int i1v = tid < 256;
  int p0 = tid / 6,          c0 = tid - 6*p0;
  int p1 = (512 + tid) / 6,  c1 = (512 + tid) - 6*p1;
  const int soff0 = LDSX + p0*40 + c0;
  const int soff1 = LDSX + p1*40 + c1;

  // init x: zeros, col6 = 1.0 (bias channel), cols 7..31 stay 0
  for (int i = tid; i < 5120; i += 512) lds[i] = 0;
  __syncthreads();
  if (tid < 128) lds[LDSX + tid*40 + 6] = 0x3F80;   // bf16 1.0
  __syncthreads();

  const float* pbase = pcls + (size_t)obj * 49152;   // 8192 pts * 6
  lds[soff0] = f2bf(pbase[tid]);
  if (i1v) lds[soff1] = f2bf(pbase[512 + tid]);
  __syncthreads();

  f32x4 macc[2];
  float sacc[2][4];
#pragma unroll
  for (int nt = 0; nt < 2; ++nt) {
    macc[nt] = (f32x4){-3e38f, -3e38f, -3e38f, -3e38f};
#pragma unroll
    for (int r = 0; r < 4; ++r) sacc[nt][r] = 0.f;
  }

  for (int cg = 0; cg < 64; ++cg) {
    // ---- layer 1: 6(+bias ch)->64. Wave: ch-tile c1t, pts [ph*64, ph*64+64)
#pragma unroll
    for (int i = 0; i < 4; ++i) {
      const int pt = ph*4 + i;
      bf16x8 b = *(const bf16x8*)(&lds[LDSX + (pt*16 + l15)*40 + q*8]);
      f32x4 d = {0.f, 0.f, 0.f, 0.f};
      d = __builtin_amdgcn_mfma_f32_16x16x32_bf16(af1, b, d, 0, 0, 0);
      *(bf16x4*)(&lds[LDSH1 + (pt*16 + l15)*72 + c1t*16 + q*4]) = pack_relu4(d);
    }
    __syncthreads();                 // x reads + h1 writes complete

    // prefetch next chunk's points (latency hidden under layer 2)
    float pf0, pf1;
    const int havenext = (cg < 63);
    if (havenext) {
      pf0 = pbase[(cg + 1)*768 + tid];
      if (i1v) pf1 = pbase[(cg + 1)*768 + 512 + tid];
    }

    // ---- layer 2: 64 -> 128, relu. Wave: ch-tile w, all 8 pt-tiles
#pragma unroll
    for (int pt = 0; pt < 8; ++pt) {
      bf16x8 b0  = *(const bf16x8*)(&lds[LDSH1 + (pt*16 + l15)*72 + q*8]);
      bf16x8 b1v = *(const bf16x8*)(&lds[LDSH1 + (pt*16 + l15)*72 + 32 + q*8]);
      f32x4 d = bias2;
      d = __builtin_amdgcn_mfma_f32_16x16x32_bf16(af2[0], b0,  d, 0, 0, 0);
      d = __builtin_amdgcn_mfma_f32_16x16x32_bf16(af2[1], b1v, d, 0, 0, 0);
      *(bf16x4*)(&lds[LDSH2 + (pt*16 + l15)*136 + w*16 + q*4]) = pack_relu4(d);
    }
    // stage prefetched points into x (x reads finished at sync above)
    if (havenext) {
      lds[soff0] = f2bf(pf0);
      if (i1v) lds[soff1] = f2bf(pf1);
    }
    __syncthreads();                 // h1 reads + h2/x writes complete

    // ---- layer 3: 128 -> 256, max-accumulate (bias applied post-max)
#pragma unroll
    for (int pt = 0; pt < 8; ++pt) {
      bf16x8 b[4];
#pragma unroll
      for (int kf = 0; kf < 4; ++kf)
        b[kf] = *(const bf16x8*)(&lds[LDSH2 + (pt*16 + l15)*136 + kf*32 + q*8]);
#pragma unroll
      for (int nt = 0; nt < 2; ++nt) {
        f32x4 d = {0.f, 0.f, 0.f, 0.f};
#pragma unroll
        for (int kf = 0; kf < 4; ++kf)
          d = __builtin_amdgcn_mfma_f32_16x16x32_bf16(af3[nt][kf], b[kf], d, 0, 0, 0);
#pragma unroll
        for (int r = 0; r < 4; ++r)
          macc[nt][r] = fmaxf(macc[nt][r], d[r]);
      }
    }
    // part boundary (512 pts = 4 chunks): reduce max over the 16 pt-lanes
    if ((cg & 3) == 3) {
#pragma unroll
      for (int nt = 0; nt < 2; ++nt) {
#pragma unroll
        for (int r = 0; r < 4; ++r) {
          float v = macc[nt][r];
          v = fmaxf(v, __shfl_xor(v, 1));
          v = fmaxf(v, __shfl_xor(v, 2));
          v = fmaxf(v, __shfl_xor(v, 4));
          v = fmaxf(v, __shfl_xor(v, 8));
          sacc[nt][r] += v;
        }
        macc[nt] = (f32x4){-3e38f, -3e38f, -3e38f, -3e38f};
      }
    }
    __syncthreads();                 // h2 reads complete; x(cg+1) visible
  }

  // =========================================================================
  // In-block per-object MLP epilogue. LDS reused as float scratch:
  // fs[256] @0, bA[256] @256, bB[256] @512, part[2][256] @768, red[8] @1280.
  // Chain: fs -(We,+16be)-> bA -(Wg1,/16+bg1,relu)-> bB -(Wg2,+bg2)-> bA
  //        -(Wc1 src+dst,+bc1,relu)-> bB -(Wc2,+bc2,relu)-> bA -.Wc3-> tanh
  // =========================================================================
  float* fls  = (float*)&lds[0];
  float* fs   = fls;
  float* bA   = fls + 256;
  float* bB   = fls + 512;
  float* part = fls + 768;
  float* redv = fls + 1280;

  // fsum[ch] = sum_parts max + 16*b3 (bias3 folded post-max; 16 parts/object)
#pragma unroll
  for (int r = 0; r < 4; ++r) {
    if (l15 == r) {
#pragma unroll
      for (int nt = 0; nt < 2; ++nt) {
        const int ch = (2*w + nt)*16 + q*4 + r;
        fs[ch] = sacc[nt][r] + 16.f * b3f[ch];
      }
    }
  }
  __syncthreads();

  const int tt = tid & 255, hh = tid >> 8;
  const int cb = hh * 128;
  float a;

  // p1: bA = fs@We + 16*be
  a = 0.f;
#pragma unroll 8
  for (int c = 0; c < 128; ++c) a += fs[cb + c] * We[(cb + c)*256 + tt];
  part[hh*256 + tt] = a;
  __syncthreads();
  if (hh == 0) bA[tt] = part[tt] + part[256 + tt] + 16.f * be[tt];
  __syncthreads();

  // p2: bB = relu(bA@Wg1 / 16 + bg1)
  a = 0.f;
#pragma unroll 8
  for (int c = 0; c < 128; ++c) a += bA[cb + c] * Wg1[(cb + c)*256 + tt];
  part[hh*256 + tt] = a;
  __syncthreads();
  if (hh == 0) bB[tt] = fmaxf((part[tt] + part[256 + tt]) * 0.0625f + bg1[tt], 0.f);
  __syncthreads();

  // p3: bA = bB@Wg2 + bg2
  a = 0.f;
#pragma unroll 8
  for (int c = 0; c < 128; ++c) a += bB[cb + c] * Wg2[(cb + c)*256 + tt];
  part[hh*256 + tt] = a;
  __syncthreads();
  if (hh == 0) bA[tt] = part[tt] + part[256 + tt] + bg2[tt];
  __syncthreads();

  // p4: bB = relu(bA@(Wc1_src + Wc1_dst) + bc1)
  a = 0.f;
#pragma unroll 8
  for (int c = 0; c < 128; ++c) {
    const float xv = bA[cb + c];
    a += xv * Wc1[(cb + c)*256 + tt];
    a += xv * Wc1[(cb + c + 256)*256 + tt];
  }
  part[hh*256 + tt] = a;
  __syncthreads();
  if (hh == 0) bB[tt] = fmaxf(part[tt] + part[256 + tt] + bc1[tt], 0.f);
  __syncthreads();

  // p5: bA = relu(bB@Wc2 + bc2)
  a = 0.f;
#pragma unroll 8
  for (int c = 0; c < 128; ++c) a += bB[cb + c] * Wc2[(cb + c)*256 + tt];
  part[hh*256 + tt] = a;
  __syncthreads();
  if (hh == 0) bA[tt] = fmaxf(part[tt] + part[256 + tt] + bc2[tt], 0.f);
  __syncthreads();

  // p6: scalar = bA . Wc3; tanh; broadcast into 16x16 (zero diagonal)
  float prod = (hh == 0) ? bA[tt] * Wc3[tt] : 0.f;
#pragma unroll
  for (int off = 1; off < 64; off <<= 1) prod += __shfl_xor(prod, off);
  if (lane == 0) redv[w] = prod;
  __syncthreads();
  if (tid == 0) redv[0] = tanhf(redv[0] + redv[1] + redv[2] + redv[3] + bc3[0]);
  __syncthreads();
  const float cv = redv[0];
  if (hh == 0)
    out[obj*256 + tt] = ((tt >> 4) == (tt & 15)) ? 0.f : cv;
}

// ---------------------------------------------------------------------------
extern "C" void kernel_launch(void* const* d_in, const int* in_sizes, int n_in,
                              void* d_out, int out_size, void* d_ws, size_t ws_size,
                              hipStream_t stream) {
  const float* pcls = (const float*)d_in[0];
  const float* W1 = (const float*)d_in[1];  const float* b1 = (const float*)d_in[2];
  const float* g1 = (const float*)d_in[3];  const float* bt1 = (const float*)d_in[4];
  const float* W2 = (const float*)d_in[5];  const float* b2 = (const float*)d_in[6];
  const float* g2 = (const float*)d_in[7];  const float* bt2 = (const float*)d_in[8];
  const float* W3 = (const float*)d_in[9];  const float* b3 = (const float*)d_in[10];
  const float* g3 = (const float*)d_in[11]; const float* bt3 = (const float*)d_in[12];
  const float* We = (const float*)d_in[13]; const float* be = (const float*)d_in[14];
  const float* Wg1 = (const float*)d_in[15]; const float* bg1 = (const float*)d_in[16];
  const float* Wg2 = (const float*)d_in[17]; const float* bg2 = (const float*)d_in[18];
  const float* Wc1 = (const float*)d_in[19]; const float* bc1 = (const float*)d_in[20];
  const float* Wc2 = (const float*)d_in[21]; const float* bc2 = (const float*)d_in[22];
  const float* Wc3 = (const float*)d_in[23]; const float* bc3 = (const float*)d_in[24];
  unsigned char* ws = (unsigned char*)d_ws;
  float* out = (float*)d_out;

  prep_kernel<<<170, 256, 0, stream>>>(W1, b1, g1, bt1, W2, b2, g2, bt2,
                                       W3, b3, g3, bt3, ws);
  pointnet_fused_kernel<<<512, 512, 0, stream>>>(
      pcls, ws, We, be, Wg1, bg1, Wg2, bg2, Wc1, bc1, Wc2, bc2, Wc3, bc3, out);
}